// Round 3
// baseline (561.402 us; speedup 1.0000x reference)
//
#include <hip/hip_runtime.h>
#include <hip/hip_bf16.h>

#define B_ROWS 4096
#define M_ROWS 65536
#define DIM 512
#define TOPK 8
#define CAP 512
#define TAU 0.132583f       // 3/sqrt(512): ~88 candidates/query expected
#define FB_N 2048           // fallback merge entries = 256 threads * 8

typedef unsigned short u16;
typedef unsigned int u32;
typedef unsigned short u16x8 __attribute__((ext_vector_type(8)));
typedef __bf16 bf16x8 __attribute__((ext_vector_type(8)));
typedef float f32x4 __attribute__((ext_vector_type(4)));

template <int N> struct IC { static constexpr int value = N; };

__device__ inline u16 f2bf(float x) {
  unsigned u = __builtin_bit_cast(unsigned, x);
  u = (u + 0x7fffu + ((u >> 16) & 1u)) >> 16;  // RNE, finite inputs only
  return (u16)u;
}

// async global->LDS, 16B per lane; lds ptr must be wave-uniform (HW adds lane*16)
__device__ inline void gl_lds16(const u16* g, u16* l) {
  __builtin_amdgcn_global_load_lds(
      (const __attribute__((address_space(1))) u32*)g,
      (__attribute__((address_space(3))) u32*)l, 16, 0, 0);
}

// ---- normalize rows -> bf16 (one wave per row) ----
__global__ __launch_bounds__(256) void norm_kernel(const float* __restrict__ in,
                                                   u16* __restrict__ out, int nrows) {
  int gw = (int)((blockIdx.x * 256 + threadIdx.x) >> 6);
  int lane = threadIdx.x & 63;
  if (gw >= nrows) return;
  const float4* r = (const float4*)(in + (size_t)gw * DIM);
  float4 v0 = r[lane * 2 + 0];
  float4 v1 = r[lane * 2 + 1];
  float ss = v0.x*v0.x + v0.y*v0.y + v0.z*v0.z + v0.w*v0.w
           + v1.x*v1.x + v1.y*v1.y + v1.z*v1.z + v1.w*v1.w;
#pragma unroll
  for (int off = 32; off > 0; off >>= 1) ss += __shfl_xor(ss, off);
  float inv = 1.0f / fmaxf(sqrtf(ss), 1e-8f);
  u16x8 o;
  o[0]=f2bf(v0.x*inv); o[1]=f2bf(v0.y*inv); o[2]=f2bf(v0.z*inv); o[3]=f2bf(v0.w*inv);
  o[4]=f2bf(v1.x*inv); o[5]=f2bf(v1.y*inv); o[6]=f2bf(v1.z*inv); o[7]=f2bf(v1.w*inv);
  *(u16x8*)(out + (size_t)gw * DIM + lane * 8) = o;
}

// ---- 256x256 tile, BK=64, 8 waves, 4-phase schedule, counted vmcnt,
//      st-swizzled LDS (pre-swizzled gl_lds source), setprio around MFMA ----
__global__ __launch_bounds__(512, 2) void gemm_select(const u16* __restrict__ qn,
                                                      const u16* __restrict__ mn,
                                                      int* __restrict__ count,
                                                      int* __restrict__ cand) {
  // per buffer: A = 2 halves x [128 rows][64 u16], B same. 2 buffers = 128 KiB.
  __shared__ u16 sA[2][2][128 * 64];
  __shared__ u16 sB[2][2][128 * 64];

  int bid0 = blockIdx.x;
  int bid = (bid0 & 7) * 512 + (bid0 >> 3);   // XCD swizzle (4096 % 8 == 0)
  int qtile = bid & 15;                       // 16 qtiles of 256
  int mtile = bid >> 4;                       // 256 mtiles of 256
  int tid = threadIdx.x;
  int lane = tid & 63;
  int w = tid >> 6;
  int wr = w >> 2, wc = w & 3;                // 2 x 4 wave grid; wave tile 128x64
  int rlo = lane & 15;
  int khi16 = (lane >> 4) << 4;               // byte offset of lane's 16B k-slice

  const u16* gA = qn + (size_t)qtile * 256 * DIM;
  const u16* gB = mn + (size_t)mtile * 256 * DIM;

  // staging geometry: thread t covers LDS bytes [t*16, +16) of a half-tile
  // (issue i adds 64 rows). row = (t*16)>>7, col = (t*16)&127, swizzled source.
  int soff = tid * 16;
  int srow = soff >> 7;                       // 0..63
  int scol = soff & 127;
  int sswz = (scol ^ ((srow & 7) << 4)) >> 1; // u16 units; srow+64 has same swz
  int ldsu = w * 512;                         // wave-uniform LDS u16 offset, issue 0

  auto stA = [&](int buf, int kt) {
#pragma unroll
    for (int h = 0; h < 2; h++)
#pragma unroll
      for (int i = 0; i < 2; i++)
        gl_lds16(gA + (size_t)(h * 128 + i * 64 + srow) * DIM + kt * 64 + sswz,
                 &sA[buf][h][i * 4096 + ldsu]);
  };
  auto stB = [&](int buf, int kt) {
#pragma unroll
    for (int h = 0; h < 2; h++)
#pragma unroll
      for (int i = 0; i < 2; i++)
        gl_lds16(gB + (size_t)(h * 128 + i * 64 + srow) * DIM + kt * 64 + sswz,
                 &sB[buf][h][i * 4096 + ldsu]);
  };
  auto rdA = [&](int buf, int mi, int ks) {
    int row = (mi << 4) + rlo;
    int cs = ((ks << 6) + khi16) ^ ((row & 7) << 4);
    return __builtin_bit_cast(bf16x8, *(const u16x8*)&sA[buf][wr][row * 64 + (cs >> 1)]);
  };
  auto rdB = [&](int buf, int ni, int ks) {
    int row = ((wc & 1) << 6) + (ni << 4) + rlo;
    int cs = ((ks << 6) + khi16) ^ ((row & 7) << 4);
    return __builtin_bit_cast(bf16x8, *(const u16x8*)&sB[buf][wc >> 1][row * 64 + (cs >> 1)]);
  };

  f32x4 acc[8][4];
#pragma unroll
  for (int i = 0; i < 8; i++)
#pragma unroll
    for (int j = 0; j < 4; j++) {
      f32x4 z = {0.f, 0.f, 0.f, 0.f};
      acc[i][j] = z;
    }
  bf16x8 aF[4][2], bF[2][2];

  // prologue: stage K-tile 0 into buf 0
  stA(0, 0);
  stB(0, 0);
  asm volatile("s_waitcnt vmcnt(0)" ::: "memory");
  __builtin_amdgcn_sched_barrier(0);
  __builtin_amdgcn_s_barrier();

  auto ktile = [&](auto bufc, int kt, bool pf) {
    constexpr int BUF = decltype(bufc)::value;
    constexpr int NBUF = BUF ^ 1;
    // ---- P1: quadrant (mh=0, nh=0); prefetch A of next tile ----
#pragma unroll
    for (int mi = 0; mi < 4; mi++)
#pragma unroll
      for (int ks = 0; ks < 2; ks++) aF[mi][ks] = rdA(BUF, mi, ks);
#pragma unroll
    for (int ni = 0; ni < 2; ni++)
#pragma unroll
      for (int ks = 0; ks < 2; ks++) bF[ni][ks] = rdB(BUF, ni, ks);
    if (pf) stA(NBUF, kt + 1);
    __builtin_amdgcn_s_barrier();
    __builtin_amdgcn_s_setprio(1);
#pragma unroll
    for (int mi = 0; mi < 4; mi++)
#pragma unroll
      for (int ni = 0; ni < 2; ni++)
#pragma unroll
        for (int ks = 0; ks < 2; ks++)
          acc[mi][ni] = __builtin_amdgcn_mfma_f32_16x16x32_bf16(aF[mi][ks], bF[ni][ks], acc[mi][ni], 0, 0, 0);
    __builtin_amdgcn_s_setprio(0);
    __builtin_amdgcn_s_barrier();
    // ---- P2: quadrant (0,1); reuse aF; prefetch B of next tile ----
#pragma unroll
    for (int ni = 0; ni < 2; ni++)
#pragma unroll
      for (int ks = 0; ks < 2; ks++) bF[ni][ks] = rdB(BUF, 2 + ni, ks);
    if (pf) stB(NBUF, kt + 1);
    __builtin_amdgcn_s_barrier();
    __builtin_amdgcn_s_setprio(1);
#pragma unroll
    for (int mi = 0; mi < 4; mi++)
#pragma unroll
      for (int ni = 0; ni < 2; ni++)
#pragma unroll
        for (int ks = 0; ks < 2; ks++)
          acc[mi][2 + ni] = __builtin_amdgcn_mfma_f32_16x16x32_bf16(aF[mi][ks], bF[ni][ks], acc[mi][2 + ni], 0, 0, 0);
    __builtin_amdgcn_s_setprio(0);
    __builtin_amdgcn_s_barrier();
    // ---- P3: quadrant (1,1); reuse bF ----
#pragma unroll
    for (int mi = 0; mi < 4; mi++)
#pragma unroll
      for (int ks = 0; ks < 2; ks++) aF[mi][ks] = rdA(BUF, 4 + mi, ks);
    __builtin_amdgcn_s_barrier();
    __builtin_amdgcn_s_setprio(1);
#pragma unroll
    for (int mi = 0; mi < 4; mi++)
#pragma unroll
      for (int ni = 0; ni < 2; ni++)
#pragma unroll
        for (int ks = 0; ks < 2; ks++)
          acc[4 + mi][2 + ni] = __builtin_amdgcn_mfma_f32_16x16x32_bf16(aF[mi][ks], bF[ni][ks], acc[4 + mi][2 + ni], 0, 0, 0);
    __builtin_amdgcn_s_setprio(0);
    __builtin_amdgcn_s_barrier();
    // ---- P4: quadrant (1,0); reuse aF; end-of-tile counted drain ----
#pragma unroll
    for (int ni = 0; ni < 2; ni++)
#pragma unroll
      for (int ks = 0; ks < 2; ks++) bF[ni][ks] = rdB(BUF, ni, ks);
    __builtin_amdgcn_s_barrier();
    __builtin_amdgcn_s_setprio(1);
#pragma unroll
    for (int mi = 0; mi < 4; mi++)
#pragma unroll
      for (int ni = 0; ni < 2; ni++)
#pragma unroll
        for (int ks = 0; ks < 2; ks++)
          acc[4 + mi][ni] = __builtin_amdgcn_mfma_f32_16x16x32_bf16(aF[mi][ks], bF[ni][ks], acc[4 + mi][ni], 0, 0, 0);
    __builtin_amdgcn_s_setprio(0);
    if (pf) {
      asm volatile("s_waitcnt vmcnt(0)" ::: "memory");  // next tile landed (issued ~3 phases ago)
      __builtin_amdgcn_sched_barrier(0);
    }
    __builtin_amdgcn_s_barrier();
  };

  for (int kt0 = 0; kt0 < 8; kt0 += 2) {
    ktile(IC<0>{}, kt0, true);
    ktile(IC<1>{}, kt0 + 1, kt0 + 1 < 7);
  }

  // epilogue: C row (query) = (lane>>4)*4 + reg, col (mem) = lane&15  [m89 layout]
  int qbase = qtile * 256 + wr * 128 + (lane >> 4) * 4;
  int mbase = mtile * 256 + wc * 64 + (lane & 15);
#pragma unroll
  for (int mi = 0; mi < 8; mi++)
#pragma unroll
    for (int ni = 0; ni < 4; ni++)
#pragma unroll
      for (int r = 0; r < 4; r++) {
        float v = acc[mi][ni][r];
        if (v > TAU) {
          int qq = qbase + mi * 16 + r;
          int mm = mbase + ni * 16;
          int pos = atomicAdd(&count[qq], 1);
          if (pos < CAP) cand[(size_t)qq * CAP + pos] = mm;
        }
      }
}

// ---- per-query: fp64 rescore of candidates, exact top-8, gather+mean ----
__global__ __launch_bounds__(256) void topk_kernel(const float* __restrict__ q,
                                                   const float* __restrict__ mem,
                                                   const int* __restrict__ count,
                                                   const int* __restrict__ cand,
                                                   float* __restrict__ out) {
  __shared__ double s_sims[FB_N];
  __shared__ int s_cidx[FB_N];
  __shared__ double s_red[4];
  __shared__ int s_redj[4];
  __shared__ int s_win[TOPK];

  int b = blockIdx.x;
  int tid = threadIdx.x;
  int lane = tid & 63;
  int w = tid >> 6;

  const float* qrow = q + (size_t)b * DIM;
  const float4* qv = (const float4*)qrow;
  float4 q0 = qv[lane * 2], q1 = qv[lane * 2 + 1];
  double q8[8] = {q0.x, q0.y, q0.z, q0.w, q1.x, q1.y, q1.z, q1.w};
  double qq = 0;
#pragma unroll
  for (int e = 0; e < 8; e++) qq += q8[e] * q8[e];
#pragma unroll
  for (int off = 32; off > 0; off >>= 1) qq += __shfl_xor(qq, off);
  double qnorm = fmax(sqrt(qq), 1e-8);

  int c = count[b];
  int n;
  if (c >= TOPK && c <= CAP) {
    for (int j = w; j < c; j += 4) {
      int mi = cand[(size_t)b * CAP + j];
      const float4* mv = (const float4*)(mem + (size_t)mi * DIM);
      float4 m0 = mv[lane * 2], m1 = mv[lane * 2 + 1];
      double m8[8] = {m0.x, m0.y, m0.z, m0.w, m1.x, m1.y, m1.z, m1.w};
      double dot = 0, mm = 0;
#pragma unroll
      for (int e = 0; e < 8; e++) { dot += q8[e] * m8[e]; mm += m8[e] * m8[e]; }
#pragma unroll
      for (int off = 32; off > 0; off >>= 1) {
        dot += __shfl_xor(dot, off);
        mm += __shfl_xor(mm, off);
      }
      if (lane == 0) {
        s_sims[j] = dot / (qnorm * fmax(sqrt(mm), 1e-8));
        s_cidx[j] = mi;
      }
    }
    n = c;
  } else {
    // fallback (cold, correctness-only): full scan, per-thread top-8, block merge
    double tv[8]; int tix[8];
#pragma unroll
    for (int r = 0; r < 8; r++) { tv[r] = -1e300; tix[r] = -1; }
    for (int row = tid; row < M_ROWS; row += 256) {
      const float4* mv = (const float4*)(mem + (size_t)row * DIM);
      double dot = 0, mm = 0;
      for (int e = 0; e < DIM / 4; e++) {
        float4 m4 = mv[e], qk = qv[e];
        dot += (double)m4.x * qk.x + (double)m4.y * qk.y + (double)m4.z * qk.z + (double)m4.w * qk.w;
        mm  += (double)m4.x * m4.x + (double)m4.y * m4.y + (double)m4.z * m4.z + (double)m4.w * m4.w;
      }
      double sim = dot / (qnorm * fmax(sqrt(mm), 1e-8));
      int am = 0;
#pragma unroll
      for (int r = 1; r < 8; r++) if (tv[r] < tv[am]) am = r;
      if (sim > tv[am]) { tv[am] = sim; tix[am] = row; }
    }
#pragma unroll
    for (int r = 0; r < 8; r++) { s_sims[tid * 8 + r] = tv[r]; s_cidx[tid * 8 + r] = tix[r]; }
    n = FB_N;
  }
  __syncthreads();

  for (int r = 0; r < TOPK; r++) {
    double best = -1e300; int bj = -1;
    for (int j = tid; j < n; j += 256) {
      double v = s_sims[j];
      if (v > best) { best = v; bj = j; }
    }
#pragma unroll
    for (int off = 32; off > 0; off >>= 1) {
      double ov = __shfl_down(best, off);
      int oj = __shfl_down(bj, off);
      if (ov > best) { best = ov; bj = oj; }
    }
    if (lane == 0) { s_red[w] = best; s_redj[w] = bj; }
    __syncthreads();
    if (tid == 0) {
      double bb = s_red[0]; int jj = s_redj[0];
      for (int i = 1; i < 4; i++) if (s_red[i] > bb) { bb = s_red[i]; jj = s_redj[i]; }
      s_win[r] = s_cidx[jj];
      s_sims[jj] = -1e300;
    }
    __syncthreads();
  }

  float ax = 0.f, ay = 0.f;
#pragma unroll
  for (int r = 0; r < TOPK; r++) {
    const float2 v = *(const float2*)(mem + (size_t)s_win[r] * DIM + tid * 2);
    ax += v.x; ay += v.y;
  }
  float2 o; o.x = ax * 0.125f; o.y = ay * 0.125f;
  *(float2*)(out + (size_t)b * DIM + tid * 2) = o;
}

extern "C" void kernel_launch(void* const* d_in, const int* in_sizes, int n_in,
                              void* d_out, int out_size, void* d_ws, size_t ws_size,
                              hipStream_t stream) {
  (void)in_sizes; (void)n_in; (void)out_size; (void)ws_size;
  const float* q = (const float*)d_in[0];
  const float* mem = (const float*)d_in[1];
  float* out = (float*)d_out;

  char* ws = (char*)d_ws;
  u16* mn = (u16*)ws;                                        // 64 MB
  u16* qn = (u16*)(ws + (size_t)M_ROWS * DIM * 2);           // 4 MB
  int* count = (int*)(ws + (size_t)M_ROWS * DIM * 2 + (size_t)B_ROWS * DIM * 2);  // 16 KB
  int* cand = (int*)((char*)count + (size_t)B_ROWS * sizeof(int));                // 8 MB

  hipMemsetAsync(count, 0, B_ROWS * sizeof(int), stream);
  norm_kernel<<<M_ROWS / 4, 256, 0, stream>>>(mem, mn, M_ROWS);
  norm_kernel<<<B_ROWS / 4, 256, 0, stream>>>(q, qn, B_ROWS);
  gemm_select<<<(B_ROWS / 256) * (M_ROWS / 256), 512, 0, stream>>>(qn, mn, count, cand);
  topk_kernel<<<B_ROWS, 256, 0, stream>>>(q, mem, count, cand, out);
}

// Round 4
// 549.313 us; speedup vs baseline: 1.0220x; 1.0220x over previous
//
#include <hip/hip_runtime.h>
#include <hip/hip_bf16.h>

#define B_ROWS 4096
#define M_ROWS 65536
#define DIM 512
#define TOPK 8
#define CAP 512
#define TAU 0.132583f       // 3/sqrt(512): ~88 candidates/query expected
#define FB_N 2048           // fallback merge entries = 256 threads * 8

typedef unsigned short u16;
typedef unsigned int u32;
typedef unsigned short u16x8 __attribute__((ext_vector_type(8)));
typedef __bf16 bf16x8 __attribute__((ext_vector_type(8)));
typedef float f32x4 __attribute__((ext_vector_type(4)));

__device__ inline u16 f2bf(float x) {
  unsigned u = __builtin_bit_cast(unsigned, x);
  u = (u + 0x7fffu + ((u >> 16) & 1u)) >> 16;  // RNE, finite inputs only
  return (u16)u;
}

// async global->LDS, 16B per lane; lds ptr must be wave-uniform (HW adds lane*16)
__device__ inline void gl_lds16(const u16* g, u16* l) {
  __builtin_amdgcn_global_load_lds(
      (const __attribute__((address_space(1))) u32*)g,
      (__attribute__((address_space(3))) u32*)l, 16, 0, 0);
}

// ---- normalize rows -> bf16 (one wave per row) ----
__global__ __launch_bounds__(256) void norm_kernel(const float* __restrict__ in,
                                                   u16* __restrict__ out, int nrows) {
  int gw = (int)((blockIdx.x * 256 + threadIdx.x) >> 6);
  int lane = threadIdx.x & 63;
  if (gw >= nrows) return;
  const float4* r = (const float4*)(in + (size_t)gw * DIM);
  float4 v0 = r[lane * 2 + 0];
  float4 v1 = r[lane * 2 + 1];
  float ss = v0.x*v0.x + v0.y*v0.y + v0.z*v0.z + v0.w*v0.w
           + v1.x*v1.x + v1.y*v1.y + v1.z*v1.z + v1.w*v1.w;
#pragma unroll
  for (int off = 32; off > 0; off >>= 1) ss += __shfl_xor(ss, off);
  float inv = 1.0f / fmaxf(sqrtf(ss), 1e-8f);
  u16x8 o;
  o[0]=f2bf(v0.x*inv); o[1]=f2bf(v0.y*inv); o[2]=f2bf(v0.z*inv); o[3]=f2bf(v0.w*inv);
  o[4]=f2bf(v1.x*inv); o[5]=f2bf(v1.y*inv); o[6]=f2bf(v1.z*inv); o[7]=f2bf(v1.w*inv);
  *(u16x8*)(out + (size_t)gw * DIM + lane * 8) = o;
}

// ---- 256x256 tile, BK=32, 8 waves, 4-deep LDS ring, counted vmcnt(8/4/0),
//      one barrier per K-step, super-row XOR swizzle, setprio around MFMA ----
__global__ __launch_bounds__(512, 2) void gemm_select(const u16* __restrict__ qn,
                                                      const u16* __restrict__ mn,
                                                      int* __restrict__ count,
                                                      int* __restrict__ cand) {
  // ring of 4 K-step buffers: A[256 rows][32 elems] (16KB) + B same -> 128 KiB
  __shared__ u16 sA[4][8192];
  __shared__ u16 sB[4][8192];

  int bid0 = blockIdx.x;
  int bid = (bid0 & 7) * 512 + (bid0 >> 3);   // XCD swizzle (4096 % 8 == 0)
  int qtile = bid & 15;                       // 16 qtiles of 256
  int mtile = bid >> 4;                       // 256 mtiles of 256
  int tid = threadIdx.x;
  int lane = tid & 63;
  int w = tid >> 6;
  int wr = w >> 2, wc = w & 3;                // 2 x 4 wave grid; wave tile 128x64
  int rlo = lane & 15;
  int khi16 = (lane >> 4) << 4;               // byte offset of lane's 16B k-slice

  const u16* gA = qn + (size_t)qtile * 256 * DIM;
  const u16* gB = mn + (size_t)mtile * 256 * DIM;

  // staging: dest byte d = i*8192 + tid*16 (linear; gl_lds dest is uniform+lane*16).
  // swizzle: within each 128B super-row, inner ^= (brow&7)<<4. Source is the
  // inverse permutation so that a swizzled READ returns logical data (rule #21).
  int brow_lo = tid >> 3;                     // 0..63 (+64 for issue 1)
  int innb = (tid & 7) << 4;                  // dest inner bytes 0..112
  int inns = innb ^ ((brow_lo & 7) << 4);     // logical inner for this dest slot
  int grow0 = brow_lo * 2 + (inns >> 6);      // logical row (issue 0)
  int gcole = (inns & 63) >> 1;               // element col within 32-elem row

  auto stA = [&](int buf, int kt) {
#pragma unroll
    for (int i = 0; i < 2; i++)
      gl_lds16(gA + (size_t)(grow0 + i * 128) * DIM + kt * 32 + gcole,
               &sA[buf][i * 4096 + w * 512]);
  };
  auto stB = [&](int buf, int kt) {
#pragma unroll
    for (int i = 0; i < 2; i++)
      gl_lds16(gB + (size_t)(grow0 + i * 128) * DIM + kt * 32 + gcole,
               &sB[buf][i * 4096 + w * 512]);
  };
  auto rdA = [&](int buf, int mi) {
    int row = wr * 128 + mi * 16 + rlo;
    int brow = row >> 1;
    int phys = (brow << 7) + ((((row & 1) << 6) + khi16) ^ ((brow & 7) << 4));
    return __builtin_bit_cast(bf16x8, *(const u16x8*)((const char*)sA[buf] + phys));
  };
  auto rdB = [&](int buf, int ni) {
    int row = wc * 64 + ni * 16 + rlo;
    int brow = row >> 1;
    int phys = (brow << 7) + ((((row & 1) << 6) + khi16) ^ ((brow & 7) << 4));
    return __builtin_bit_cast(bf16x8, *(const u16x8*)((const char*)sB[buf] + phys));
  };

  f32x4 acc[8][4];
#pragma unroll
  for (int i = 0; i < 8; i++)
#pragma unroll
    for (int j = 0; j < 4; j++) {
      f32x4 z = {0.f, 0.f, 0.f, 0.f};
      acc[i][j] = z;
    }

  // one K-step: barrier (buf ready + prev readers done), 12 ds_read_b128,
  // issue next stage (stays in flight across future barriers), 32 MFMA.
  auto step = [&](int buf, int nbuf, int ktn, bool st) {
    __builtin_amdgcn_s_barrier();
    bf16x8 aF[8], bF[4];
#pragma unroll
    for (int mi = 0; mi < 8; mi++) aF[mi] = rdA(buf, mi);
#pragma unroll
    for (int ni = 0; ni < 4; ni++) bF[ni] = rdB(buf, ni);
    if (st) { stA(nbuf, ktn); stB(nbuf, ktn); }
    __builtin_amdgcn_s_setprio(1);
#pragma unroll
    for (int mi = 0; mi < 8; mi++)
#pragma unroll
      for (int ni = 0; ni < 4; ni++)
        acc[mi][ni] = __builtin_amdgcn_mfma_f32_16x16x32_bf16(aF[mi], bF[ni], acc[mi][ni], 0, 0, 0);
    __builtin_amdgcn_s_setprio(0);
  };

  // prologue: stage K-steps 0,1,2 into bufs 0,1,2 (12 loads in flight)
  stA(0, 0); stB(0, 0);
  stA(1, 1); stB(1, 1);
  stA(2, 2); stB(2, 2);

  for (int t = 0; t < 13; t++) {
    // wait for buf t's 4 loads (oldest); keep t+1,t+2's 8 in flight
    asm volatile("s_waitcnt vmcnt(8)" ::: "memory");
    step(t & 3, (t + 3) & 3, t + 3, true);
  }
  asm volatile("s_waitcnt vmcnt(8)" ::: "memory");   // t=13: 14,15 in flight
  step(1, 0, 0, false);
  asm volatile("s_waitcnt vmcnt(4)" ::: "memory");   // t=14: 15 in flight
  step(2, 0, 0, false);
  asm volatile("s_waitcnt vmcnt(0)" ::: "memory");   // t=15: drain
  step(3, 0, 0, false);

  // epilogue: C row (query) = (lane>>4)*4 + reg, col (mem) = lane&15  [m89 layout]
  int qbase = qtile * 256 + wr * 128 + (lane >> 4) * 4;
  int mbase = mtile * 256 + wc * 64 + (lane & 15);
#pragma unroll
  for (int mi = 0; mi < 8; mi++)
#pragma unroll
    for (int ni = 0; ni < 4; ni++)
#pragma unroll
      for (int r = 0; r < 4; r++) {
        float v = acc[mi][ni][r];
        if (v > TAU) {
          int qq = qbase + mi * 16 + r;
          int mm = mbase + ni * 16;
          int pos = atomicAdd(&count[qq], 1);
          if (pos < CAP) cand[(size_t)qq * CAP + pos] = mm;
        }
      }
}

// ---- per-query: fp64 rescore of candidates, exact top-8, gather+mean ----
__global__ __launch_bounds__(256) void topk_kernel(const float* __restrict__ q,
                                                   const float* __restrict__ mem,
                                                   const int* __restrict__ count,
                                                   const int* __restrict__ cand,
                                                   float* __restrict__ out) {
  __shared__ double s_sims[FB_N];
  __shared__ int s_cidx[FB_N];
  __shared__ double s_red[4];
  __shared__ int s_redj[4];
  __shared__ int s_win[TOPK];

  int b = blockIdx.x;
  int tid = threadIdx.x;
  int lane = tid & 63;
  int w = tid >> 6;

  const float* qrow = q + (size_t)b * DIM;
  const float4* qv = (const float4*)qrow;
  float4 q0 = qv[lane * 2], q1 = qv[lane * 2 + 1];
  double q8[8] = {q0.x, q0.y, q0.z, q0.w, q1.x, q1.y, q1.z, q1.w};
  double qq = 0;
#pragma unroll
  for (int e = 0; e < 8; e++) qq += q8[e] * q8[e];
#pragma unroll
  for (int off = 32; off > 0; off >>= 1) qq += __shfl_xor(qq, off);
  double qnorm = fmax(sqrt(qq), 1e-8);

  int c = count[b];
  int n;
  if (c >= TOPK && c <= CAP) {
    for (int j = w; j < c; j += 4) {
      int mi = cand[(size_t)b * CAP + j];
      const float4* mv = (const float4*)(mem + (size_t)mi * DIM);
      float4 m0 = mv[lane * 2], m1 = mv[lane * 2 + 1];
      double m8[8] = {m0.x, m0.y, m0.z, m0.w, m1.x, m1.y, m1.z, m1.w};
      double dot = 0, mm = 0;
#pragma unroll
      for (int e = 0; e < 8; e++) { dot += q8[e] * m8[e]; mm += m8[e] * m8[e]; }
#pragma unroll
      for (int off = 32; off > 0; off >>= 1) {
        dot += __shfl_xor(dot, off);
        mm += __shfl_xor(mm, off);
      }
      if (lane == 0) {
        s_sims[j] = dot / (qnorm * fmax(sqrt(mm), 1e-8));
        s_cidx[j] = mi;
      }
    }
    n = c;
  } else {
    // fallback (cold, correctness-only): full scan, per-thread top-8, block merge
    double tv[8]; int tix[8];
#pragma unroll
    for (int r = 0; r < 8; r++) { tv[r] = -1e300; tix[r] = -1; }
    for (int row = tid; row < M_ROWS; row += 256) {
      const float4* mv = (const float4*)(mem + (size_t)row * DIM);
      double dot = 0, mm = 0;
      for (int e = 0; e < DIM / 4; e++) {
        float4 m4 = mv[e], qk = qv[e];
        dot += (double)m4.x * qk.x + (double)m4.y * qk.y + (double)m4.z * qk.z + (double)m4.w * qk.w;
        mm  += (double)m4.x * m4.x + (double)m4.y * m4.y + (double)m4.z * m4.z + (double)m4.w * m4.w;
      }
      double sim = dot / (qnorm * fmax(sqrt(mm), 1e-8));
      int am = 0;
#pragma unroll
      for (int r = 1; r < 8; r++) if (tv[r] < tv[am]) am = r;
      if (sim > tv[am]) { tv[am] = sim; tix[am] = row; }
    }
#pragma unroll
    for (int r = 0; r < 8; r++) { s_sims[tid * 8 + r] = tv[r]; s_cidx[tid * 8 + r] = tix[r]; }
    n = FB_N;
  }
  __syncthreads();

  for (int r = 0; r < TOPK; r++) {
    double best = -1e300; int bj = -1;
    for (int j = tid; j < n; j += 256) {
      double v = s_sims[j];
      if (v > best) { best = v; bj = j; }
    }
#pragma unroll
    for (int off = 32; off > 0; off >>= 1) {
      double ov = __shfl_down(best, off);
      int oj = __shfl_down(bj, off);
      if (ov > best) { best = ov; bj = oj; }
    }
    if (lane == 0) { s_red[w] = best; s_redj[w] = bj; }
    __syncthreads();
    if (tid == 0) {
      double bb = s_red[0]; int jj = s_redj[0];
      for (int i = 1; i < 4; i++) if (s_red[i] > bb) { bb = s_red[i]; jj = s_redj[i]; }
      s_win[r] = s_cidx[jj];
      s_sims[jj] = -1e300;
    }
    __syncthreads();
  }

  float ax = 0.f, ay = 0.f;
#pragma unroll
  for (int r = 0; r < TOPK; r++) {
    const float2 v = *(const float2*)(mem + (size_t)s_win[r] * DIM + tid * 2);
    ax += v.x; ay += v.y;
  }
  float2 o; o.x = ax * 0.125f; o.y = ay * 0.125f;
  *(float2*)(out + (size_t)b * DIM + tid * 2) = o;
}

extern "C" void kernel_launch(void* const* d_in, const int* in_sizes, int n_in,
                              void* d_out, int out_size, void* d_ws, size_t ws_size,
                              hipStream_t stream) {
  (void)in_sizes; (void)n_in; (void)out_size; (void)ws_size;
  const float* q = (const float*)d_in[0];
  const float* mem = (const float*)d_in[1];
  float* out = (float*)d_out;

  char* ws = (char*)d_ws;
  u16* mn = (u16*)ws;                                        // 64 MB
  u16* qn = (u16*)(ws + (size_t)M_ROWS * DIM * 2);           // 4 MB
  int* count = (int*)(ws + (size_t)M_ROWS * DIM * 2 + (size_t)B_ROWS * DIM * 2);  // 16 KB
  int* cand = (int*)((char*)count + (size_t)B_ROWS * sizeof(int));                // 8 MB

  hipMemsetAsync(count, 0, B_ROWS * sizeof(int), stream);
  norm_kernel<<<M_ROWS / 4, 256, 0, stream>>>(mem, mn, M_ROWS);
  norm_kernel<<<B_ROWS / 4, 256, 0, stream>>>(q, qn, B_ROWS);
  gemm_select<<<(B_ROWS / 256) * (M_ROWS / 256), 512, 0, stream>>>(qn, mn, count, cand);
  topk_kernel<<<B_ROWS, 256, 0, stream>>>(q, mem, count, cand, out);
}